// Round 10
// baseline (535.401 us; speedup 1.0000x reference)
//
#include <hip/hip_runtime.h>
#include <hip/hip_bf16.h>
#include <math.h>

#define NCLS 19
#define MCOMP 5
#define AFEAT 64
#define IGNORE_L 255
#define LOG2PI 1.8378770664093453f

// 20 classes x 8 component-slots = 160 rows; slot 5 of wal = mean_target (sim),
// slots 6..7 and class 19 are pads.
#define ROWS 160
// ws byte offsets
#define WAM_B 0                      // bf16 [160][128] : 40960 B ([nl | iv], row-major)
#define WAL_B 40960                  // bf16 k-major [10 tiles][8 kslots][16 rows][8] : 20480 B
#define CST_B 61440                  // f32  [160]      : 640 B (pads = 1e30)
#define DR_B  62080                  // f32  [20]       : 80 B  (DR[19] = 0)
#define ACC_B 62208                  // f32  [2]        : sum, cnt
#define VAL_B 62272                  // u64  [4096]     : validity bitmask

typedef __attribute__((ext_vector_type(8))) short bf16x8;
typedef __attribute__((ext_vector_type(4))) float f32x4;

__device__ inline short f2b(float f) {
    __hip_bfloat16 h = __float2bfloat16(f);
    return *reinterpret_cast<short*>(&h);
}

// wal k-major offset (in shorts) for global row r (0..159), channel a (0..63)
__device__ __host__ inline int wal_off(int r, int a) {
    int tile = r >> 4, rr = r & 15, s = a >> 3, j = a & 7;
    return ((tile * 8 + s) * 16 + rr) * 8 + j;
}

// ---------------- precompute: permuted bf16 weights + constants ----------------
__global__ void precompute_kernel(const float* __restrict__ mean,
                                  const float* __restrict__ cov,
                                  const float* __restrict__ tmem,
                                  const float* __restrict__ ct,
                                  const float* __restrict__ cs,
                                  char* __restrict__ wsb) {
    int blk = blockIdx.x;
    int a = threadIdx.x;  // 64 threads
    short* wam = (short*)(wsb + WAM_B);
    short* wal = (short*)(wsb + WAL_B);
    float* cst = (float*)(wsb + CST_B);
    float* dr  = (float*)(wsb + DR_B);
    float* acc = (float*)(wsb + ACC_B);

    if (blk < ROWS) {
        int r = blk, c = r >> 3, m = r & 7;
        if (c < NCLS && m < MCOMP) {
            int k = c * MCOMP + m;
            float lo = mean[k * AFEAT + a];
            float cv = cov[k * AFEAT + a];
            float iv = 1.0f / (cv * cv);
            wam[r * 128 + a]      = f2b(-2.0f * lo * iv);  // k-half 0: pairs with f
            wam[r * 128 + 64 + a] = f2b(iv);               // k-half 1: pairs with q=f^2
            wal[wal_off(r, a)]    = f2b(lo);
            float s1 = lo * lo * iv;
            float s2 = logf(cv);
            for (int off = 32; off > 0; off >>= 1) {
                s1 += __shfl_xor(s1, off, 64);
                s2 += __shfl_xor(s2, off, 64);
            }
            if (a == 0) cst[r] = AFEAT * LOG2PI + 2.0f * s2 + s1;
        } else {
            wam[r * 128 + a] = 0; wam[r * 128 + 64 + a] = 0;
            // slot 5 of real classes is owned by the mt blocks below (avoid race)
            if (!(m == 5 && c < NCLS)) wal[wal_off(r, a)] = 0;
            if (a == 0) cst[r] = 1e30f;   // pad: lp -> -inf
        }
    } else if (blk < ROWS + 20) {
        int c = blk - ROWS;
        int r = ((c >> 1) << 4) + 8 * (c & 1) + 5;   // slot-5 row of class c
        if (c < NCLS) {
            const float* p = tmem + ((size_t)c * AFEAT + a) * 100;
            float s = 0.f;
            for (int j = 0; j < 100; ++j) s += p[j];
            s *= 0.01f;
            float n2 = s * s;
            for (int off = 32; off > 0; off >>= 1) n2 += __shfl_xor(n2, off, 64);
            float den = fmaxf(sqrtf(n2), 1e-12f);
            wal[wal_off(r, a)] = f2b(s / den);
        } else {
            wal[wal_off(r, a)] = 0;      // class-19 slot-5 pad
        }
    } else {
        if (a < 20) {
            float rr = 0.f;
            if (a < NCLS) {
                rr = ct[a] / cs[a];
                if (isnan(rr)) rr = 0.f;
                else if (isinf(rr)) rr = (rr > 0.f) ? 3.402823466e38f : -3.402823466e38f;
            }
            dr[a] = rr;
        }
        if (a == 32) { acc[0] = 0.f; acc[1] = 0.f; }
    }
}

// ---------------- validity bitmask (majority >= 12/16 of a real class) ----------
__global__ void valid_kernel(const int* __restrict__ mask,
                             unsigned long long* __restrict__ vwords) {
    int n = blockIdx.x * 256 + threadIdx.x;
    int b = n >> 16, rem = n & 65535, y = rem >> 8, x = rem & 255;
    const int* mp = mask + (((size_t)b << 10) + ((size_t)y << 2)) * 1024 + ((size_t)x << 2);
    int v[16];
#pragma unroll
    for (int r = 0; r < 4; ++r) {
        int4 q = *reinterpret_cast<const int4*>(mp + (size_t)r * 1024);
        v[r * 4 + 0] = q.x; v[r * 4 + 1] = q.y; v[r * 4 + 2] = q.z; v[r * 4 + 3] = q.w;
    }
    bool valid = false;
#pragma unroll
    for (int i = 0; i < 16; ++i) {
        int cnt = 0;
#pragma unroll
        for (int j = 0; j < 16; ++j) cnt += (v[j] == v[i]) ? 1 : 0;
        if (v[i] != IGNORE_L && cnt >= 12) valid = true;
    }
    unsigned long long bm = __ballot(valid);
    if ((threadIdx.x & 63) == 0) vwords[n >> 6] = bm;
}

// ---------------- main MFMA kernel: 1 tile (16 px) per wave ----------
// sim is folded into the logits GEMM (mt at slot 5) -> sd = q[1] on g in {1,3}.
__global__ __launch_bounds__(512, 6)
void protogmm_kernel(const float* __restrict__ feat,
                     const char* __restrict__ wsb,
                     const unsigned long long* __restrict__ vwords,
                     float* __restrict__ accg) {
    __shared__ short wamL[ROWS * 128];   // 40960 B, slot-swizzled
    __shared__ float cstL[ROWS];         // 640 B
    __shared__ float ldrL[20];           // 80 B (log of dist ratio)

    int tid = threadIdx.x;
    {
        const uint4* s0 = (const uint4*)(wsb + WAM_B);
        for (int i = tid; i < 2560; i += 512) {
            int row = i >> 4, slot = i & 15;
            *(uint4*)((char*)wamL + row * 256 + ((slot ^ (row & 7)) << 4)) = s0[i];
        }
        const float* s2 = (const float*)(wsb + CST_B);
        if (tid < ROWS) cstL[tid] = s2[tid];
        const float* s4 = (const float*)(wsb + DR_B);
        if (tid < 20) ldrL[tid] = __logf(s4[tid]);   // log(0) = -inf for pad class
    }
    __syncthreads();

    int lane = tid & 63, l15 = lane & 15, g = lane >> 4, rx = l15 & 7;
    int wv = blockIdx.x * 8 + (tid >> 6);   // wave id == tile id (0..16383)
    int n0 = wv << 4;
    int b = n0 >> 16, y = (n0 >> 8) & 255, x0 = n0 & 255;
    const char* walG = wsb + WAL_B;

    // ---- load feature chunks (a in [8g,8g+8) and [32+8g,+8)), norm, pack bf16
    bf16x8 F[4];
    {
        const float* fb = feat + (size_t)b * (AFEAT * 65536) + y * 256 + x0 + l15;
        float fa[8], fc[8];
        float n2 = 0.f;
#pragma unroll
        for (int j = 0; j < 8; ++j) {
            fa[j] = fb[(size_t)(8 * g + j) * 65536];
            fc[j] = fb[(size_t)(32 + 8 * g + j) * 65536];
        }
#pragma unroll
        for (int j = 0; j < 8; ++j) {
            n2 = fmaf(fa[j], fa[j], n2);
            n2 = fmaf(fc[j], fc[j], n2);
        }
        n2 += __shfl_xor(n2, 16, 64);
        n2 += __shfl_xor(n2, 32, 64);
        float inv = 1.0f / fmaxf(sqrtf(n2), 1e-12f);
#pragma unroll
        for (int j = 0; j < 8; ++j) {
            float u = fa[j] * inv, w2 = fc[j] * inv;
            F[0][j] = f2b(u);
            F[1][j] = f2b(w2);
            F[2][j] = f2b(u * u);
            F[3][j] = f2b(w2 * w2);
        }
    }

    int p = g >> 1;                 // class parity this lane tracks
    float ls = 0.f;                 // sum over classes of exp(logits_max)
    float bW = -3.4e38f, bc = 0.f, bl = 0.f;

#pragma unroll 1
    for (int t = 0; t < 10; ++t) {
        // ---- maha GEMM: acc = cst + [nl|iv] . [f|q]   (weights from LDS)
        f32x4 acc = *(const f32x4*)(cstL + 16 * t + 4 * g);
#pragma unroll
        for (int kt = 0; kt < 4; ++kt) {
            bf16x8 wa = *(const bf16x8*)((char*)wamL + (16 * t + l15) * 256 +
                                         (((4 * kt + g) ^ rx) << 4));
            acc = __builtin_amdgcn_mfma_f32_16x16x32_bf16(wa, F[kt], acc, 0, 0, 0);
        }

        // ---- logits(+sim) GEMM: weights from global, k-major coalesced layout
        f32x4 q = {0.f, 0.f, 0.f, 0.f};
#pragma unroll
        for (int kt = 0; kt < 2; ++kt) {
            bf16x8 wl = *(const bf16x8*)(walG +
                        (((t * 8 + 4 * kt + g) * 16 + l15) << 4));
            q = __builtin_amdgcn_mfma_f32_16x16x32_bf16(wl, F[kt], q, 0, 0, 0);
        }
        float sd = q[1];   // slot-5 row = f . mean_target; valid on g==1 (even), g==3 (odd)

        // ---- per-class logits max (mask slots 5..7 on odd g; class-19 pad)
        float d0 = q[0] * 0.01f, d1 = q[1] * 0.01f;
        float d2 = q[2] * 0.01f, d3 = q[3] * 0.01f;
        if (g & 1) { d1 = -1e30f; d2 = -1e30f; d3 = -1e30f; }
        float lt = fmaxf(fmaxf(d0, d1), fmaxf(d2, d3));
        if (t == 9 && (g & 2)) lt = -1e30f;
        float lmx = fmaxf(lt, __shfl_xor(lt, 16, 64));
        ls += __expf(lmx);

        // ---- per-class maha LSE (xor16 only: class spans one g-pair)
        float mn = fminf(fminf(acc[0], acc[1]), fminf(acc[2], acc[3]));
        mn = fminf(mn, __shfl_xor(mn, 16, 64));
        float mx = -0.5f * mn;
        float e0 = __expf(fmaf(acc[0], -0.5f, -mx));
        float e1 = __expf(fmaf(acc[1], -0.5f, -mx));
        float e2 = __expf(fmaf(acc[2], -0.5f, -mx));
        float e3 = __expf(fmaf(acc[3], -0.5f, -mx));
        float st = (e0 + e1) + (e2 + e3);
        float lse = mx + __logf(st + __shfl_xor(st, 16, 64));

        // ---- log-space value compare (softmax denominators cancel)
        float W = ldrL[2 * t + p] + sd + lse;
        if (W > bW) { bW = W; bc = (float)(2 * t + p); bl = lmx; }
    }

    // ---- merge the two parities (valid data on g==1 / g==3; xor32 pairs them)
    {
        float ov = __shfl_xor(bW, 32, 64);
        float oc = __shfl_xor(bc, 32, 64);
        float ol = __shfl_xor(bl, 32, 64);
        bool take = (ov > bW) || (ov == bW && oc < bc);
        bW = take ? ov : bW; bl = take ? ol : bl; bc = take ? oc : bc;
        ls += __shfl_xor(ls, 32, 64);
    }
    float ce = __logf(ls) - bl;

    // ---- validity + accumulate (valid result lives on g==1 lanes)
    unsigned long long w = vwords[wv >> 2];
    float vb = (float)((w >> (((wv & 3) << 4) + l15)) & 1ull);
    float own = (g == 1) ? 1.f : 0.f;
    float cesum  = own * vb * ce;
    float cntsum = own * vb;

#pragma unroll
    for (int off = 32; off > 0; off >>= 1) {
        cesum  += __shfl_xor(cesum, off, 64);
        cntsum += __shfl_xor(cntsum, off, 64);
    }
    if (lane == 0) {
        atomicAdd(&accg[0], cesum);
        atomicAdd(&accg[1], cntsum);
    }
}

__global__ void finalize_kernel(const float* __restrict__ acc, float* __restrict__ out) {
    out[0] = acc[0] / fmaxf(acc[1], 1.0f);
}

extern "C" void kernel_launch(void* const* d_in, const int* in_sizes, int n_in,
                              void* d_out, int out_size, void* d_ws, size_t ws_size,
                              hipStream_t stream) {
    const float* feat = (const float*)d_in[0];
    const int*   mask = (const int*)d_in[1];
    const float* mean = (const float*)d_in[2];
    const float* cov  = (const float*)d_in[3];
    const float* tmem = (const float*)d_in[4];
    const float* ct   = (const float*)d_in[5];
    const float* cs   = (const float*)d_in[6];
    float* out = (float*)d_out;
    char*  wsb = (char*)d_ws;

    precompute_kernel<<<ROWS + 20 + 1, 64, 0, stream>>>(mean, cov, tmem, ct, cs, wsb);
    valid_kernel<<<1024, 256, 0, stream>>>(mask, (unsigned long long*)(wsb + VAL_B));
    protogmm_kernel<<<2048, 512, 0, stream>>>(feat, wsb,
                                              (const unsigned long long*)(wsb + VAL_B),
                                              (float*)(wsb + ACC_B));
    finalize_kernel<<<1, 1, 0, stream>>>((const float*)(wsb + ACC_B), out);
}

// Round 12
// 232.728 us; speedup vs baseline: 2.3005x; 2.3005x over previous
//
#include <hip/hip_runtime.h>
#include <hip/hip_bf16.h>
#include <math.h>

#define NCLS 19
#define MCOMP 5
#define AFEAT 64
#define IGNORE_L 255
#define LOG2PI 1.8378770664093453f

// 20 classes x 8 component-slots = 160 rows; slot 5 of wal = mean_target (sim),
// slots 6..7 and class 19 are pads.
#define ROWS 160
// ws byte offsets
#define WAM_B 0                      // bf16 [160][128] : 40960 B ([nl | iv], row-major)
#define WAL_B 40960                  // bf16 [160][64]  : 20480 B (loc; slot5=mean_target)
#define CST_B 61440                  // f32  [160]      : 640 B (pads = 1e30)
#define DR_B  62080                  // f32  [20]       : 80 B  (DR[19] = 0)
#define ACC_B 62208                  // f32  [2]        : sum, cnt
#define VAL_B 62272                  // u64  [4096]     : validity bitmask

typedef __attribute__((ext_vector_type(8))) short bf16x8;
typedef __attribute__((ext_vector_type(4))) float f32x4;

__device__ inline short f2b(float f) {
    __hip_bfloat16 h = __float2bfloat16(f);
    return *reinterpret_cast<short*>(&h);
}

// ---------------- precompute: permuted bf16 weights + constants ----------------
__global__ void precompute_kernel(const float* __restrict__ mean,
                                  const float* __restrict__ cov,
                                  const float* __restrict__ tmem,
                                  const float* __restrict__ ct,
                                  const float* __restrict__ cs,
                                  char* __restrict__ wsb) {
    int blk = blockIdx.x;
    int a = threadIdx.x;  // 64 threads
    short* wam = (short*)(wsb + WAM_B);
    short* wal = (short*)(wsb + WAL_B);
    float* cst = (float*)(wsb + CST_B);
    float* dr  = (float*)(wsb + DR_B);
    float* acc = (float*)(wsb + ACC_B);

    if (blk < ROWS) {
        int r = blk, c = r >> 3, m = r & 7;
        if (c < NCLS && m < MCOMP) {
            int k = c * MCOMP + m;
            float lo = mean[k * AFEAT + a];
            float cv = cov[k * AFEAT + a];
            float iv = 1.0f / (cv * cv);
            wam[r * 128 + a]      = f2b(-2.0f * lo * iv);  // k-half 0: pairs with f
            wam[r * 128 + 64 + a] = f2b(iv);               // k-half 1: pairs with q=f^2
            wal[r * 64 + a]       = f2b(lo);
            float s1 = lo * lo * iv;
            float s2 = logf(cv);
            for (int off = 32; off > 0; off >>= 1) {
                s1 += __shfl_xor(s1, off, 64);
                s2 += __shfl_xor(s2, off, 64);
            }
            if (a == 0) cst[r] = AFEAT * LOG2PI + 2.0f * s2 + s1;
        } else {
            wam[r * 128 + a] = 0; wam[r * 128 + 64 + a] = 0;
            // slot 5 of real classes is owned by the mt blocks below (avoid race)
            if (!(m == 5 && c < NCLS)) wal[r * 64 + a] = 0;
            if (a == 0) cst[r] = 1e30f;   // pad: lp -> -inf
        }
    } else if (blk < ROWS + 20) {
        int c = blk - ROWS;
        int r = ((c >> 1) << 4) + ((c & 1) << 3) + 5;   // slot-5 row of class c
        if (c < NCLS) {
            const float* p = tmem + ((size_t)c * AFEAT + a) * 100;
            float s = 0.f;
            for (int j = 0; j < 100; ++j) s += p[j];
            s *= 0.01f;
            float n2 = s * s;
            for (int off = 32; off > 0; off >>= 1) n2 += __shfl_xor(n2, off, 64);
            float den = fmaxf(sqrtf(n2), 1e-12f);
            wal[r * 64 + a] = f2b(s / den);
        } else {
            wal[r * 64 + a] = 0;      // class-19 slot-5 pad
        }
    } else {
        if (a < 20) {
            float rr = 0.f;
            if (a < NCLS) {
                rr = ct[a] / cs[a];
                if (isnan(rr)) rr = 0.f;
                else if (isinf(rr)) rr = (rr > 0.f) ? 3.402823466e38f : -3.402823466e38f;
            }
            dr[a] = rr;
        }
        if (a == 32) { acc[0] = 0.f; acc[1] = 0.f; }
    }
}

// ---------------- validity bitmask (majority >= 12/16 of a real class) ----------
__global__ void valid_kernel(const int* __restrict__ mask,
                             unsigned long long* __restrict__ vwords) {
    int n = blockIdx.x * 256 + threadIdx.x;
    int b = n >> 16, rem = n & 65535, y = rem >> 8, x = rem & 255;
    const int* mp = mask + (((size_t)b << 10) + ((size_t)y << 2)) * 1024 + ((size_t)x << 2);
    int v[16];
#pragma unroll
    for (int r = 0; r < 4; ++r) {
        int4 q = *reinterpret_cast<const int4*>(mp + (size_t)r * 1024);
        v[r * 4 + 0] = q.x; v[r * 4 + 1] = q.y; v[r * 4 + 2] = q.z; v[r * 4 + 3] = q.w;
    }
    bool valid = false;
#pragma unroll
    for (int i = 0; i < 16; ++i) {
        int cnt = 0;
#pragma unroll
        for (int j = 0; j < 16; ++j) cnt += (v[j] == v[i]) ? 1 : 0;
        if (v[i] != IGNORE_L && cnt >= 12) valid = true;
    }
    unsigned long long bm = __ballot(valid);
    if ((threadIdx.x & 63) == 0) vwords[n >> 6] = bm;
}

// ---------------- main MFMA kernel ----------------
// 512 threads = 8 waves; each wave does 4 tiles of 16 pixels.
// sim folded into logits GEMM slot 5 -> sd = q[1] on g in {1,3}.
// Log-space per-class terms -> t-iterations fully independent (pipelinable).
__global__ void protogmm_kernel(const float* __restrict__ feat,
                                const char* __restrict__ wsb,
                                const unsigned long long* __restrict__ vwords,
                                float* __restrict__ accg) {
    __shared__ short wamL[ROWS * 128];   // 40960 B, slot-swizzled
    __shared__ short walL[ROWS * 64];    // 20480 B, slot-swizzled
    __shared__ float cstL[ROWS];         // 640 B
    __shared__ float ldrL[20];           // 80 B (log dist-ratio)

    int tid = threadIdx.x;
    {
        const uint4* s0 = (const uint4*)(wsb + WAM_B);
        for (int i = tid; i < 2560; i += 512) {
            int row = i >> 4, slot = i & 15;
            *(uint4*)((char*)wamL + row * 256 + ((slot ^ (row & 7)) << 4)) = s0[i];
        }
        const uint4* s1 = (const uint4*)(wsb + WAL_B);
        for (int i = tid; i < 1280; i += 512) {
            int row = i >> 3, slot = i & 7;
            *(uint4*)((char*)walL + row * 128 + ((slot ^ (row & 7)) << 4)) = s1[i];
        }
        const float* s2 = (const float*)(wsb + CST_B);
        if (tid < ROWS) cstL[tid] = s2[tid];
        const float* s4 = (const float*)(wsb + DR_B);
        if (tid < 20) ldrL[tid] = __logf(s4[tid]);   // log(0) = -inf for pad class
    }
    __syncthreads();

    int lane = tid & 63, l15 = lane & 15, g = lane >> 4, rx = l15 & 7;
    int wv = blockIdx.x * 8 + (tid >> 6);
    int p = g >> 1;  // class parity this lane tracks

    float cesum = 0.f, cntsum = 0.f;

#pragma unroll 1
    for (int it = 0; it < 4; ++it) {
        int tile = wv * 4 + it;
        int n0 = tile << 4;
        int b = n0 >> 16, y = (n0 >> 8) & 255, x0 = n0 & 255;

        // ---- load feature chunks (a in [8g,8g+8) and [32+8g,+8)), norm, pack bf16
        bf16x8 F[4];
        {
            const float* fb = feat + (size_t)b * (AFEAT * 65536) + y * 256 + x0 + l15;
            float fa[8], fc[8];
            float n2 = 0.f;
#pragma unroll
            for (int j = 0; j < 8; ++j) {
                fa[j] = fb[(size_t)(8 * g + j) * 65536];
                fc[j] = fb[(size_t)(32 + 8 * g + j) * 65536];
            }
#pragma unroll
            for (int j = 0; j < 8; ++j) {
                n2 = fmaf(fa[j], fa[j], n2);
                n2 = fmaf(fc[j], fc[j], n2);
            }
            n2 += __shfl_xor(n2, 16, 64);
            n2 += __shfl_xor(n2, 32, 64);
            float inv = 1.0f / fmaxf(sqrtf(n2), 1e-12f);
#pragma unroll
            for (int j = 0; j < 8; ++j) {
                float u = fa[j] * inv, w2 = fc[j] * inv;
                F[0][j] = f2b(u);
                F[1][j] = f2b(w2);
                F[2][j] = f2b(u * u);
                F[3][j] = f2b(w2 * w2);
            }
        }

        float ls = 0.f;                 // sum over classes of exp(logits_max)
        float bW = -3.4e38f, bc = 0.f, bl = 0.f;

#pragma unroll 2
        for (int t = 0; t < 10; ++t) {
            // ---- maha GEMM: acc = cst + [nl|iv] . [f|q]
            f32x4 acc = *(const f32x4*)(cstL + 16 * t + 4 * g);
#pragma unroll
            for (int kt = 0; kt < 4; ++kt) {
                bf16x8 wa = *(const bf16x8*)((char*)wamL + (16 * t + l15) * 256 +
                                             (((4 * kt + g) ^ rx) << 4));
                acc = __builtin_amdgcn_mfma_f32_16x16x32_bf16(wa, F[kt], acc, 0, 0, 0);
            }

            // ---- logits(+sim) GEMM
            f32x4 q = {0.f, 0.f, 0.f, 0.f};
#pragma unroll
            for (int kt = 0; kt < 2; ++kt) {
                bf16x8 wl = *(const bf16x8*)((char*)walL + (16 * t + l15) * 128 +
                                             (((4 * kt + g) ^ rx) << 4));
                q = __builtin_amdgcn_mfma_f32_16x16x32_bf16(wl, F[kt], q, 0, 0, 0);
            }
            float sd = q[1];   // slot-5 row = f.mean_target; valid on g==1 / g==3

            // ---- per-class logits max (mask slots 5..7 on odd g; class-19 pad)
            float d0 = q[0] * 0.01f, d1 = q[1] * 0.01f;
            float d2 = q[2] * 0.01f, d3 = q[3] * 0.01f;
            if (g & 1) { d1 = -1e30f; d2 = -1e30f; d3 = -1e30f; }
            float lt = fmaxf(fmaxf(d0, d1), fmaxf(d2, d3));
            if (t == 9 && (g & 2)) lt = -1e30f;
            float lmx = fmaxf(lt, __shfl_xor(lt, 16, 64));
            ls += __expf(lmx);

            // ---- per-class maha LSE (xor16 only: class spans one g-pair)
            float mn = fminf(fminf(acc[0], acc[1]), fminf(acc[2], acc[3]));
            mn = fminf(mn, __shfl_xor(mn, 16, 64));
            float mx = -0.5f * mn;
            float e0 = __expf(fmaf(acc[0], -0.5f, -mx));
            float e1 = __expf(fmaf(acc[1], -0.5f, -mx));
            float e2 = __expf(fmaf(acc[2], -0.5f, -mx));
            float e3 = __expf(fmaf(acc[3], -0.5f, -mx));
            float st = (e0 + e1) + (e2 + e3);
            float lse = mx + __logf(st + __shfl_xor(st, 16, 64));

            // ---- log-space value compare (softmax denominators cancel)
            float W = ldrL[2 * t + p] + sd + lse;
            if (W > bW) { bW = W; bc = (float)(2 * t + p); bl = lmx; }
        }

        // ---- merge the two parities (valid data on g==1 / g==3; xor32 pairs them)
        {
            float ov = __shfl_xor(bW, 32, 64);
            float oc = __shfl_xor(bc, 32, 64);
            float ol = __shfl_xor(bl, 32, 64);
            bool take = (ov > bW) || (ov == bW && oc < bc);
            bW = take ? ov : bW; bl = take ? ol : bl; bc = take ? oc : bc;
            ls += __shfl_xor(ls, 32, 64);
        }
        float ce = __logf(ls) - bl;

        // ---- validity + accumulate (valid result lives on g==1 lanes)
        unsigned long long w = vwords[tile >> 2];
        float vb = (float)((w >> (((tile & 3) << 4) + l15)) & 1ull);
        float own = (g == 1) ? 1.f : 0.f;
        cesum  = fmaf(own * vb, ce, cesum);
        cntsum += own * vb;
    }

    // ---- wave reduce + atomic
#pragma unroll
    for (int off = 32; off > 0; off >>= 1) {
        cesum  += __shfl_xor(cesum, off, 64);
        cntsum += __shfl_xor(cntsum, off, 64);
    }
    if (lane == 0) {
        atomicAdd(&accg[0], cesum);
        atomicAdd(&accg[1], cntsum);
    }
}

__global__ void finalize_kernel(const float* __restrict__ acc, float* __restrict__ out) {
    out[0] = acc[0] / fmaxf(acc[1], 1.0f);
}

extern "C" void kernel_launch(void* const* d_in, const int* in_sizes, int n_in,
                              void* d_out, int out_size, void* d_ws, size_t ws_size,
                              hipStream_t stream) {
    const float* feat = (const float*)d_in[0];
    const int*   mask = (const int*)d_in[1];
    const float* mean = (const float*)d_in[2];
    const float* cov  = (const float*)d_in[3];
    const float* tmem = (const float*)d_in[4];
    const float* ct   = (const float*)d_in[5];
    const float* cs   = (const float*)d_in[6];
    float* out = (float*)d_out;
    char*  wsb = (char*)d_ws;

    precompute_kernel<<<ROWS + 20 + 1, 64, 0, stream>>>(mean, cov, tmem, ct, cs, wsb);
    valid_kernel<<<1024, 256, 0, stream>>>(mask, (unsigned long long*)(wsb + VAL_B));
    protogmm_kernel<<<512, 512, 0, stream>>>(feat, wsb,
                                             (const unsigned long long*)(wsb + VAL_B),
                                             (float*)(wsb + ACC_B));
    finalize_kernel<<<1, 1, 0, stream>>>((const float*)(wsb + ACC_B), out);
}